// Round 8
// baseline (710.035 us; speedup 1.0000x reference)
//
#include <hip/hip_runtime.h>
#include <hip/hip_bf16.h>
#include <math.h>

#define NN 20000          // nodes
#define NE 320000         // edges (without self loops)
#define ET (NE + NN)      // edges + self loops
#define NG 64             // graphs
#define HEADS 4
#define HID 128
#define OUTC (HEADS * HID)   // 512
#define SLOPE 0.2f
#define NINF (-1e30f)

__device__ __forceinline__ float lrelu(float v) { return v > 0.f ? v : SLOPE * v; }

// ---------------- CSR build ----------------
__global__ void k_hist(const int* __restrict__ ei, int* __restrict__ deg) {
  int e = blockIdx.x * blockDim.x + threadIdx.x;
  if (e >= ET) return;
  int dst = (e < NE) ? ei[NE + e] : (e - NE);
  atomicAdd(&deg[dst], 1);
}

__global__ void k_scan(const int* __restrict__ deg, int* __restrict__ row_start,
                       int* __restrict__ cursor) {
  __shared__ int sums[1024];
  int tid = threadIdx.x;
  const int PER = (NN + 1023) / 1024;   // 20
  int base = tid * PER;
  int local = 0;
  for (int i = 0; i < PER; ++i) { int idx = base + i; if (idx < NN) local += deg[idx]; }
  sums[tid] = local;
  __syncthreads();
  for (int off = 1; off < 1024; off <<= 1) {
    int v = (tid >= off) ? sums[tid - off] : 0;
    __syncthreads();
    sums[tid] += v;
    __syncthreads();
  }
  int run = sums[tid] - local;  // exclusive prefix
  for (int i = 0; i < PER; ++i) {
    int idx = base + i;
    if (idx < NN) { row_start[idx] = run; cursor[idx] = run; run += deg[idx]; }
  }
  if (tid == 1023) row_start[NN] = sums[1023];
}

__global__ void k_scatter(const int* __restrict__ ei, int* __restrict__ cursor,
                          int* __restrict__ csr_src) {
  int e = blockIdx.x * blockDim.x + threadIdx.x;
  if (e >= ET) return;
  int src, dst;
  if (e < NE) { src = ei[e]; dst = ei[NE + e]; }
  else        { src = e - NE; dst = src; }
  int pos = atomicAdd(&cursor[dst], 1);
  csr_src[pos] = src;
}

// ---------------- tiled GEMM: h = x @ W,  x [NN,K], W [K,512] ----------------
template <int K, int BK>
__global__ void k_gemm_t(const float* __restrict__ x, const float* __restrict__ W,
                         float* __restrict__ h) {
  const int BM = 64, BN = 64;
  __shared__ float sAT[BK][BM + 4];
  __shared__ float sB[BK][BN];
  int tid = threadIdx.x;
  int r0 = blockIdx.y * BM;
  int cb = blockIdx.x * BN;
  int tx = tid & 15, ty = tid >> 4;
  int m0 = ty * 4, n0 = tx * 4;
  float acc[4][4] = {};
  for (int k0 = 0; k0 < K; k0 += BK) {
    const int AF4 = BM * BK / 4;
    for (int idx = tid; idx < AF4; idx += 256) {
      int r = idx / (BK / 4);
      int kq = idx % (BK / 4);
      int row = r0 + r;
      float4 v = make_float4(0.f, 0.f, 0.f, 0.f);
      if (row < NN) v = *reinterpret_cast<const float4*>(&x[(size_t)row * K + k0 + kq * 4]);
      sAT[kq * 4 + 0][r] = v.x;
      sAT[kq * 4 + 1][r] = v.y;
      sAT[kq * 4 + 2][r] = v.z;
      sAT[kq * 4 + 3][r] = v.w;
    }
    const int BF4 = BK * BN / 4;
    for (int idx = tid; idx < BF4; idx += 256) {
      int k = idx / 16, nq = idx & 15;
      float4 v = *reinterpret_cast<const float4*>(&W[(size_t)(k0 + k) * OUTC + cb + nq * 4]);
      *reinterpret_cast<float4*>(&sB[k][nq * 4]) = v;
    }
    __syncthreads();
#pragma unroll 4
    for (int kk = 0; kk < BK; ++kk) {
      float4 a = *reinterpret_cast<const float4*>(&sAT[kk][m0]);
      float4 b = *reinterpret_cast<const float4*>(&sB[kk][n0]);
      acc[0][0] += a.x * b.x; acc[0][1] += a.x * b.y; acc[0][2] += a.x * b.z; acc[0][3] += a.x * b.w;
      acc[1][0] += a.y * b.x; acc[1][1] += a.y * b.y; acc[1][2] += a.y * b.z; acc[1][3] += a.y * b.w;
      acc[2][0] += a.z * b.x; acc[2][1] += a.z * b.y; acc[2][2] += a.z * b.z; acc[2][3] += a.z * b.w;
      acc[3][0] += a.w * b.x; acc[3][1] += a.w * b.y; acc[3][2] += a.w * b.z; acc[3][3] += a.w * b.w;
    }
    __syncthreads();
  }
#pragma unroll
  for (int i = 0; i < 4; ++i) {
    int row = r0 + m0 + i;
    if (row < NN) {
      float4 v = make_float4(acc[i][0], acc[i][1], acc[i][2], acc[i][3]);
      *reinterpret_cast<float4*>(&h[(size_t)row * OUTC + cb + n0]) = v;
    }
  }
}

// ---------------- attention logits per node (float4, 128 thr/node) ----------------
__global__ void k_esd(const float* __restrict__ h, const float* __restrict__ as,
                      const float* __restrict__ ad, float* __restrict__ e_src,
                      float* __restrict__ e_dst) {
  int n = blockIdx.x;
  int tid = threadIdx.x;       // 128
  int head = tid >> 5, q = tid & 31;
  float4 hv = *reinterpret_cast<const float4*>(&h[(size_t)n * OUTC + head * HID + q * 4]);
  float4 av = *reinterpret_cast<const float4*>(&as[head * HID + q * 4]);
  float4 dv = *reinterpret_cast<const float4*>(&ad[head * HID + q * 4]);
  float ps = hv.x * av.x + hv.y * av.y + hv.z * av.z + hv.w * av.w;
  float pd = hv.x * dv.x + hv.y * dv.y + hv.z * dv.z + hv.w * dv.w;
#pragma unroll
  for (int off = 1; off < 32; off <<= 1) {
    ps += __shfl_xor(ps, off);
    pd += __shfl_xor(pd, off);
  }
  if (q == 0) { e_src[n * HEADS + head] = ps; e_dst[n * HEADS + head] = pd; }
}

// ---------------- edge-softmax prep: one wave per node ----------------
// Computes per-head max, exp numerators (stored per CSR slot as float4),
// and invd[n] = 0.25/denominator per head. No barriers, no LDS.
__global__ void __launch_bounds__(256) k_prep(
    const float* __restrict__ es, const float* __restrict__ ed,
    const int* __restrict__ row_start, const int* __restrict__ csr_src,
    float* __restrict__ ealpha, float* __restrict__ invd) {
  int wid = threadIdx.x >> 6;
  int lane = threadIdx.x & 63;
  int n = blockIdx.x * 4 + wid;          // NN % 4 == 0
  int start = row_start[n];
  int deg = row_start[n + 1] - start;
  float4 edv = *reinterpret_cast<const float4*>(&ed[(size_t)n * 4]);
  // pass 1: per-head max
  float m0 = NINF, m1 = NINF, m2 = NINF, m3 = NINF;
  for (int k = lane; k < deg; k += 64) {
    int s = csr_src[start + k];
    float4 e4 = *reinterpret_cast<const float4*>(&es[(size_t)s * 4]);
    m0 = fmaxf(m0, lrelu(e4.x + edv.x));
    m1 = fmaxf(m1, lrelu(e4.y + edv.y));
    m2 = fmaxf(m2, lrelu(e4.z + edv.z));
    m3 = fmaxf(m3, lrelu(e4.w + edv.w));
  }
#pragma unroll
  for (int off = 1; off < 64; off <<= 1) {
    m0 = fmaxf(m0, __shfl_xor(m0, off));
    m1 = fmaxf(m1, __shfl_xor(m1, off));
    m2 = fmaxf(m2, __shfl_xor(m2, off));
    m3 = fmaxf(m3, __shfl_xor(m3, off));
  }
  // pass 2: exp numerators -> ealpha (coalesced float4 store), accumulate denom
  float d0 = 0.f, d1 = 0.f, d2 = 0.f, d3 = 0.f;
  for (int k = lane; k < deg; k += 64) {
    int s = csr_src[start + k];
    float4 e4 = *reinterpret_cast<const float4*>(&es[(size_t)s * 4]);
    float4 ex;
    ex.x = __expf(lrelu(e4.x + edv.x) - m0);
    ex.y = __expf(lrelu(e4.y + edv.y) - m1);
    ex.z = __expf(lrelu(e4.z + edv.z) - m2);
    ex.w = __expf(lrelu(e4.w + edv.w) - m3);
    *reinterpret_cast<float4*>(&ealpha[(size_t)(start + k) * 4]) = ex;
    d0 += ex.x; d1 += ex.y; d2 += ex.z; d3 += ex.w;
  }
#pragma unroll
  for (int off = 1; off < 64; off <<= 1) {
    d0 += __shfl_xor(d0, off);
    d1 += __shfl_xor(d1, off);
    d2 += __shfl_xor(d2, off);
    d3 += __shfl_xor(d3, off);
  }
  if (lane == 0) {
    float4 iv;
    iv.x = 0.25f / d0; iv.y = 0.25f / d1; iv.z = 0.25f / d2; iv.w = 0.25f / d3;
    *reinterpret_cast<float4*>(&invd[(size_t)n * 4]) = iv;
  }
}

// ---------------- weighted gather: ONE WAVE PER NODE (round-3 shape, staged alpha) ----------------
// 4 waves/block, no barriers/LDS. Lane owns 8 channels (c0 = lane*8), head = lane>>4.
// Per edge: broadcast csr load + per-head-group alpha load + 2 float4 h loads.
// 4-edge unroll: live set ~52 VGPR (proven no-spill shape from round 3).
// POOL=1: layer-3 variant accumulates per-graph sums atomically.
template <int POOL>
__global__ void __launch_bounds__(256) k_gather(
    const float* __restrict__ h, const float* __restrict__ ealpha,
    const float* __restrict__ invd, const int* __restrict__ row_start,
    const int* __restrict__ csr_src, const float* __restrict__ bias,
    float* __restrict__ xout, const int* __restrict__ batch,
    float* __restrict__ gsums) {
  int wid = threadIdx.x >> 6;
  int lane = threadIdx.x & 63;
  int n = blockIdx.x * 4 + wid;          // NN % 4 == 0, wave-uniform, no barriers
  int start = row_start[n];
  int deg = row_start[n + 1] - start;
  int head = lane >> 4;
  int c0 = lane * 8;
  const int* sp = csr_src + start;
  const float* ap = ealpha + (size_t)start * 4 + head;
  float4 accA = make_float4(0.f, 0.f, 0.f, 0.f);
  float4 accB = make_float4(0.f, 0.f, 0.f, 0.f);
  int j = 0;
  for (; j + 4 <= deg; j += 4) {
    int s0 = sp[j + 0], s1 = sp[j + 1], s2 = sp[j + 2], s3 = sp[j + 3];
    float a0 = ap[(j + 0) * 4], a1 = ap[(j + 1) * 4];
    float a2 = ap[(j + 2) * 4], a3 = ap[(j + 3) * 4];
    const float4* p0 = reinterpret_cast<const float4*>(&h[(size_t)s0 * OUTC + c0]);
    const float4* p1 = reinterpret_cast<const float4*>(&h[(size_t)s1 * OUTC + c0]);
    const float4* p2 = reinterpret_cast<const float4*>(&h[(size_t)s2 * OUTC + c0]);
    const float4* p3 = reinterpret_cast<const float4*>(&h[(size_t)s3 * OUTC + c0]);
    float4 h0a = p0[0], h0b = p0[1];
    float4 h1a = p1[0], h1b = p1[1];
    float4 h2a = p2[0], h2b = p2[1];
    float4 h3a = p3[0], h3b = p3[1];
    accA.x += a0 * h0a.x; accA.y += a0 * h0a.y; accA.z += a0 * h0a.z; accA.w += a0 * h0a.w;
    accB.x += a0 * h0b.x; accB.y += a0 * h0b.y; accB.z += a0 * h0b.z; accB.w += a0 * h0b.w;
    accA.x += a1 * h1a.x; accA.y += a1 * h1a.y; accA.z += a1 * h1a.z; accA.w += a1 * h1a.w;
    accB.x += a1 * h1b.x; accB.y += a1 * h1b.y; accB.z += a1 * h1b.z; accB.w += a1 * h1b.w;
    accA.x += a2 * h2a.x; accA.y += a2 * h2a.y; accA.z += a2 * h2a.z; accA.w += a2 * h2a.w;
    accB.x += a2 * h2b.x; accB.y += a2 * h2b.y; accB.z += a2 * h2b.z; accB.w += a2 * h2b.w;
    accA.x += a3 * h3a.x; accA.y += a3 * h3a.y; accA.z += a3 * h3a.z; accA.w += a3 * h3a.w;
    accB.x += a3 * h3b.x; accB.y += a3 * h3b.y; accB.z += a3 * h3b.z; accB.w += a3 * h3b.w;
  }
  for (; j < deg; ++j) {
    int sj = sp[j];
    float a = ap[j * 4];
    const float4* p = reinterpret_cast<const float4*>(&h[(size_t)sj * OUTC + c0]);
    float4 ha = p[0], hb = p[1];
    accA.x += a * ha.x; accA.y += a * ha.y; accA.z += a * ha.z; accA.w += a * ha.w;
    accB.x += a * hb.x; accB.y += a * hb.y; accB.z += a * hb.z; accB.w += a * hb.w;
  }
  // normalize (invd carries the 0.25 head-mean factor)
  float4 iv4 = *reinterpret_cast<const float4*>(&invd[(size_t)n * 4]);
  float myinv = (head == 0) ? iv4.x : (head == 1) ? iv4.y : (head == 2) ? iv4.z : iv4.w;
  accA.x *= myinv; accA.y *= myinv; accA.z *= myinv; accA.w *= myinv;
  accB.x *= myinv; accB.y *= myinv; accB.z *= myinv; accB.w *= myinv;
  // head-sum across lane groups: lanes l, l^16, l^32, l^48 hold same head-local channels
#pragma unroll
  for (int off = 16; off < 64; off <<= 1) {
    accA.x += __shfl_xor(accA.x, off); accA.y += __shfl_xor(accA.y, off);
    accA.z += __shfl_xor(accA.z, off); accA.w += __shfl_xor(accA.w, off);
    accB.x += __shfl_xor(accB.x, off); accB.y += __shfl_xor(accB.y, off);
    accB.z += __shfl_xor(accB.z, off); accB.w += __shfl_xor(accB.w, off);
  }
  if (lane < 16) {
    int cc = lane * 8;
    float4 b0 = *reinterpret_cast<const float4*>(&bias[cc]);
    float4 b1 = *reinterpret_cast<const float4*>(&bias[cc + 4]);
    float4 o0, o1;
    o0.x = fmaxf(accA.x + b0.x, 0.f);
    o0.y = fmaxf(accA.y + b0.y, 0.f);
    o0.z = fmaxf(accA.z + b0.z, 0.f);
    o0.w = fmaxf(accA.w + b0.w, 0.f);
    o1.x = fmaxf(accB.x + b1.x, 0.f);
    o1.y = fmaxf(accB.y + b1.y, 0.f);
    o1.z = fmaxf(accB.z + b1.z, 0.f);
    o1.w = fmaxf(accB.w + b1.w, 0.f);
    if (POOL) {
      int g = batch[n];
      float* gp = &gsums[(size_t)g * HID + cc];
      atomicAdd(&gp[0], o0.x); atomicAdd(&gp[1], o0.y);
      atomicAdd(&gp[2], o0.z); atomicAdd(&gp[3], o0.w);
      atomicAdd(&gp[4], o1.x); atomicAdd(&gp[5], o1.y);
      atomicAdd(&gp[6], o1.z); atomicAdd(&gp[7], o1.w);
    } else {
      *reinterpret_cast<float4*>(&xout[(size_t)n * HID + cc]) = o0;
      *reinterpret_cast<float4*>(&xout[(size_t)n * HID + cc + 4]) = o1;
    }
  }
}

// ---------------- MLP head (counts via binary search over sorted batch) ----------------
__global__ void k_mlp(const float* __restrict__ sums, const int* __restrict__ batch,
                      const float* __restrict__ bst, const float* __restrict__ M1,
                      const float* __restrict__ mb1, const float* __restrict__ M2,
                      const float* __restrict__ mb2, const float* __restrict__ M3,
                      const float* __restrict__ mb3, float* __restrict__ out) {
  int g = blockIdx.x, tid = threadIdx.x;  // 128 threads
  int lo = 0, hi = NN;
  while (lo < hi) { int mid = (lo + hi) >> 1; if (batch[mid] < g) lo = mid + 1; else hi = mid; }
  int s = lo;
  lo = s; hi = NN;
  while (lo < hi) { int mid = (lo + hi) >> 1; if (batch[mid] < g + 1) lo = mid + 1; else hi = mid; }
  int e = lo;
  float cnt = (float)(e - s);
  float pooled = sums[g * HID + tid] / fmaxf(cnt, 1.f);
  __shared__ float z[HID + 1];
  __shared__ float z1[HID];
  __shared__ float z2[64];
  z[tid] = pooled;
  if (tid == 0) z[HID] = log1pf(bst[g]);
  __syncthreads();
  float a1 = mb1[tid];
  for (int k = 0; k < HID + 1; ++k) a1 += z[k] * M1[k * HID + tid];
  z1[tid] = a1 > 0.f ? a1 : 0.f;
  __syncthreads();
  if (tid < 64) {
    float a2 = mb2[tid];
    for (int k = 0; k < HID; ++k) a2 += z1[k] * M2[k * 64 + tid];
    z2[tid] = a2 > 0.f ? a2 : 0.f;
  }
  __syncthreads();
  if (tid < 2) {
    float a3 = mb3[tid];
    for (int k = 0; k < 64; ++k) a3 += z2[k] * M3[k * 2 + tid];
    out[g * 2 + tid] = a3;
  }
}

extern "C" void kernel_launch(void* const* d_in, const int* in_sizes, int n_in,
                              void* d_out, int out_size, void* d_ws, size_t ws_size,
                              hipStream_t stream) {
  const float* x   = (const float*)d_in[0];
  const int*   ei  = (const int*)d_in[1];
  const int*   bat = (const int*)d_in[2];
  const float* bst = (const float*)d_in[3];
  const float* W1 = (const float*)d_in[4];
  const float* as1 = (const float*)d_in[5];
  const float* ad1 = (const float*)d_in[6];
  const float* b1 = (const float*)d_in[7];
  const float* W2 = (const float*)d_in[8];
  const float* as2 = (const float*)d_in[9];
  const float* ad2 = (const float*)d_in[10];
  const float* b2 = (const float*)d_in[11];
  const float* W3 = (const float*)d_in[12];
  const float* as3 = (const float*)d_in[13];
  const float* ad3 = (const float*)d_in[14];
  const float* b3 = (const float*)d_in[15];
  const float* M1 = (const float*)d_in[16];
  const float* mb1 = (const float*)d_in[17];
  const float* M2 = (const float*)d_in[18];
  const float* mb2 = (const float*)d_in[19];
  const float* M3 = (const float*)d_in[20];
  const float* mb3 = (const float*)d_in[21];
  float* out = (float*)d_out;

  char* ws = (char*)d_ws;
  auto alloc = [&](size_t bytes) -> void* {
    void* p = (void*)ws;
    ws += (bytes + 255) & ~(size_t)255;
    return p;
  };
  float* h_buf  = (float*)alloc((size_t)NN * OUTC * 4);
  float* x_buf  = (float*)alloc((size_t)NN * HID * 4);
  float* e_src  = (float*)alloc((size_t)NN * 4 * 4);
  float* e_dst  = (float*)alloc((size_t)NN * 4 * 4);
  int*   deg    = (int*)alloc((size_t)NN * 4);
  int*   rowst  = (int*)alloc((size_t)(NN + 1) * 4);
  int*   cursor = (int*)alloc((size_t)NN * 4);
  int*   csr    = (int*)alloc((size_t)ET * 4);
  float* ealpha = (float*)alloc((size_t)ET * 4 * 4);
  float* invd   = (float*)alloc((size_t)NN * 4 * 4);
  float* gsums  = (float*)alloc((size_t)NG * HID * 4);

  // CSR by destination
  hipMemsetAsync(deg, 0, (size_t)NN * 4, stream);
  hipMemsetAsync(gsums, 0, (size_t)NG * HID * 4, stream);
  k_hist<<<(ET + 255) / 256, 256, 0, stream>>>(ei, deg);
  k_scan<<<1, 1024, 0, stream>>>(deg, rowst, cursor);
  k_scatter<<<(ET + 255) / 256, 256, 0, stream>>>(ei, cursor, csr);

  dim3 ggrid(OUTC / 64, (NN + 63) / 64);
  dim3 pgrid(NN / 4);
  dim3 agrid(NN / 4);
  // layer 1
  k_gemm_t<12, 12><<<ggrid, 256, 0, stream>>>(x, W1, h_buf);
  k_esd<<<NN, 128, 0, stream>>>(h_buf, as1, ad1, e_src, e_dst);
  k_prep<<<pgrid, 256, 0, stream>>>(e_src, e_dst, rowst, csr, ealpha, invd);
  k_gather<0><<<agrid, 256, 0, stream>>>(h_buf, ealpha, invd, rowst, csr, b1, x_buf, bat, gsums);
  // layer 2
  k_gemm_t<128, 64><<<ggrid, 256, 0, stream>>>(x_buf, W2, h_buf);
  k_esd<<<NN, 128, 0, stream>>>(h_buf, as2, ad2, e_src, e_dst);
  k_prep<<<pgrid, 256, 0, stream>>>(e_src, e_dst, rowst, csr, ealpha, invd);
  k_gather<0><<<agrid, 256, 0, stream>>>(h_buf, ealpha, invd, rowst, csr, b2, x_buf, bat, gsums);
  // layer 3 (pool fused via atomics into gsums)
  k_gemm_t<128, 64><<<ggrid, 256, 0, stream>>>(x_buf, W3, h_buf);
  k_esd<<<NN, 128, 0, stream>>>(h_buf, as3, ad3, e_src, e_dst);
  k_prep<<<pgrid, 256, 0, stream>>>(e_src, e_dst, rowst, csr, ealpha, invd);
  k_gather<1><<<agrid, 256, 0, stream>>>(h_buf, ealpha, invd, rowst, csr, b3, x_buf, bat, gsums);
  // MLP head
  k_mlp<<<NG, 128, 0, stream>>>(gsums, bat, bst, M1, mb1, M2, mb2, M3, mb3, out);
}

// Round 9
// 705.584 us; speedup vs baseline: 1.0063x; 1.0063x over previous
//
#include <hip/hip_runtime.h>
#include <hip/hip_bf16.h>
#include <math.h>

#define NN 20000          // nodes
#define NE 320000         // edges (without self loops)
#define ET (NE + NN)      // edges + self loops
#define NG 64             // graphs
#define HEADS 4
#define HID 128
#define OUTC (HEADS * HID)   // 512
#define SLOPE 0.2f
#define NINF (-1e30f)

__device__ __forceinline__ float lrelu(float v) { return v > 0.f ? v : SLOPE * v; }

// ---------------- CSR build ----------------
__global__ void k_hist(const int* __restrict__ ei, int* __restrict__ deg) {
  int e = blockIdx.x * blockDim.x + threadIdx.x;
  if (e >= ET) return;
  int dst = (e < NE) ? ei[NE + e] : (e - NE);
  atomicAdd(&deg[dst], 1);
}

__global__ void k_scan(const int* __restrict__ deg, int* __restrict__ row_start,
                       int* __restrict__ cursor) {
  __shared__ int sums[1024];
  int tid = threadIdx.x;
  const int PER = (NN + 1023) / 1024;   // 20
  int base = tid * PER;
  int local = 0;
  for (int i = 0; i < PER; ++i) { int idx = base + i; if (idx < NN) local += deg[idx]; }
  sums[tid] = local;
  __syncthreads();
  for (int off = 1; off < 1024; off <<= 1) {
    int v = (tid >= off) ? sums[tid - off] : 0;
    __syncthreads();
    sums[tid] += v;
    __syncthreads();
  }
  int run = sums[tid] - local;  // exclusive prefix
  for (int i = 0; i < PER; ++i) {
    int idx = base + i;
    if (idx < NN) { row_start[idx] = run; cursor[idx] = run; run += deg[idx]; }
  }
  if (tid == 1023) row_start[NN] = sums[1023];
}

__global__ void k_scatter(const int* __restrict__ ei, int* __restrict__ cursor,
                          int* __restrict__ csr_src) {
  int e = blockIdx.x * blockDim.x + threadIdx.x;
  if (e >= ET) return;
  int src, dst;
  if (e < NE) { src = ei[e]; dst = ei[NE + e]; }
  else        { src = e - NE; dst = src; }
  int pos = atomicAdd(&cursor[dst], 1);
  csr_src[pos] = src;
}

// ---------------- tiled GEMM: h = x @ W,  x [NN,K], W [K,512] ----------------
template <int K, int BK>
__global__ void k_gemm_t(const float* __restrict__ x, const float* __restrict__ W,
                         float* __restrict__ h) {
  const int BM = 64, BN = 64;
  __shared__ float sAT[BK][BM + 4];
  __shared__ float sB[BK][BN];
  int tid = threadIdx.x;
  int r0 = blockIdx.y * BM;
  int cb = blockIdx.x * BN;
  int tx = tid & 15, ty = tid >> 4;
  int m0 = ty * 4, n0 = tx * 4;
  float acc[4][4] = {};
  for (int k0 = 0; k0 < K; k0 += BK) {
    const int AF4 = BM * BK / 4;
    for (int idx = tid; idx < AF4; idx += 256) {
      int r = idx / (BK / 4);
      int kq = idx % (BK / 4);
      int row = r0 + r;
      float4 v = make_float4(0.f, 0.f, 0.f, 0.f);
      if (row < NN) v = *reinterpret_cast<const float4*>(&x[(size_t)row * K + k0 + kq * 4]);
      sAT[kq * 4 + 0][r] = v.x;
      sAT[kq * 4 + 1][r] = v.y;
      sAT[kq * 4 + 2][r] = v.z;
      sAT[kq * 4 + 3][r] = v.w;
    }
    const int BF4 = BK * BN / 4;
    for (int idx = tid; idx < BF4; idx += 256) {
      int k = idx / 16, nq = idx & 15;
      float4 v = *reinterpret_cast<const float4*>(&W[(size_t)(k0 + k) * OUTC + cb + nq * 4]);
      *reinterpret_cast<float4*>(&sB[k][nq * 4]) = v;
    }
    __syncthreads();
#pragma unroll 4
    for (int kk = 0; kk < BK; ++kk) {
      float4 a = *reinterpret_cast<const float4*>(&sAT[kk][m0]);
      float4 b = *reinterpret_cast<const float4*>(&sB[kk][n0]);
      acc[0][0] += a.x * b.x; acc[0][1] += a.x * b.y; acc[0][2] += a.x * b.z; acc[0][3] += a.x * b.w;
      acc[1][0] += a.y * b.x; acc[1][1] += a.y * b.y; acc[1][2] += a.y * b.z; acc[1][3] += a.y * b.w;
      acc[2][0] += a.z * b.x; acc[2][1] += a.z * b.y; acc[2][2] += a.z * b.z; acc[2][3] += a.z * b.w;
      acc[3][0] += a.w * b.x; acc[3][1] += a.w * b.y; acc[3][2] += a.w * b.z; acc[3][3] += a.w * b.w;
    }
    __syncthreads();
  }
#pragma unroll
  for (int i = 0; i < 4; ++i) {
    int row = r0 + m0 + i;
    if (row < NN) {
      float4 v = make_float4(acc[i][0], acc[i][1], acc[i][2], acc[i][3]);
      *reinterpret_cast<float4*>(&h[(size_t)row * OUTC + cb + n0]) = v;
    }
  }
}

// ---------------- attention logits per node (float4, 128 thr/node) ----------------
__global__ void k_esd(const float* __restrict__ h, const float* __restrict__ as,
                      const float* __restrict__ ad, float* __restrict__ e_src,
                      float* __restrict__ e_dst) {
  int n = blockIdx.x;
  int tid = threadIdx.x;       // 128
  int head = tid >> 5, q = tid & 31;
  float4 hv = *reinterpret_cast<const float4*>(&h[(size_t)n * OUTC + head * HID + q * 4]);
  float4 av = *reinterpret_cast<const float4*>(&as[head * HID + q * 4]);
  float4 dv = *reinterpret_cast<const float4*>(&ad[head * HID + q * 4]);
  float ps = hv.x * av.x + hv.y * av.y + hv.z * av.z + hv.w * av.w;
  float pd = hv.x * dv.x + hv.y * dv.y + hv.z * dv.z + hv.w * dv.w;
#pragma unroll
  for (int off = 1; off < 32; off <<= 1) {
    ps += __shfl_xor(ps, off);
    pd += __shfl_xor(pd, off);
  }
  if (q == 0) { e_src[n * HEADS + head] = ps; e_dst[n * HEADS + head] = pd; }
}

// ---------------- edge-softmax prep: one wave per node ----------------
__global__ void __launch_bounds__(256) k_prep(
    const float* __restrict__ es, const float* __restrict__ ed,
    const int* __restrict__ row_start, const int* __restrict__ csr_src,
    float* __restrict__ ealpha, float* __restrict__ invd) {
  int wid = threadIdx.x >> 6;
  int lane = threadIdx.x & 63;
  int n = blockIdx.x * 4 + wid;          // NN % 4 == 0
  int start = row_start[n];
  int deg = row_start[n + 1] - start;
  float4 edv = *reinterpret_cast<const float4*>(&ed[(size_t)n * 4]);
  // pass 1: per-head max
  float m0 = NINF, m1 = NINF, m2 = NINF, m3 = NINF;
  for (int k = lane; k < deg; k += 64) {
    int s = csr_src[start + k];
    float4 e4 = *reinterpret_cast<const float4*>(&es[(size_t)s * 4]);
    m0 = fmaxf(m0, lrelu(e4.x + edv.x));
    m1 = fmaxf(m1, lrelu(e4.y + edv.y));
    m2 = fmaxf(m2, lrelu(e4.z + edv.z));
    m3 = fmaxf(m3, lrelu(e4.w + edv.w));
  }
#pragma unroll
  for (int off = 1; off < 64; off <<= 1) {
    m0 = fmaxf(m0, __shfl_xor(m0, off));
    m1 = fmaxf(m1, __shfl_xor(m1, off));
    m2 = fmaxf(m2, __shfl_xor(m2, off));
    m3 = fmaxf(m3, __shfl_xor(m3, off));
  }
  // pass 2: exp numerators -> ealpha (coalesced float4 store), accumulate denom
  float d0 = 0.f, d1 = 0.f, d2 = 0.f, d3 = 0.f;
  for (int k = lane; k < deg; k += 64) {
    int s = csr_src[start + k];
    float4 e4 = *reinterpret_cast<const float4*>(&es[(size_t)s * 4]);
    float4 ex;
    ex.x = __expf(lrelu(e4.x + edv.x) - m0);
    ex.y = __expf(lrelu(e4.y + edv.y) - m1);
    ex.z = __expf(lrelu(e4.z + edv.z) - m2);
    ex.w = __expf(lrelu(e4.w + edv.w) - m3);
    *reinterpret_cast<float4*>(&ealpha[(size_t)(start + k) * 4]) = ex;
    d0 += ex.x; d1 += ex.y; d2 += ex.z; d3 += ex.w;
  }
#pragma unroll
  for (int off = 1; off < 64; off <<= 1) {
    d0 += __shfl_xor(d0, off);
    d1 += __shfl_xor(d1, off);
    d2 += __shfl_xor(d2, off);
    d3 += __shfl_xor(d3, off);
  }
  if (lane == 0) {
    float4 iv;
    iv.x = 0.25f / d0; iv.y = 0.25f / d1; iv.z = 0.25f / d2; iv.w = 0.25f / d3;
    *reinterpret_cast<float4*>(&invd[(size_t)n * 4]) = iv;
  }
}

// ---------------- weighted gather: ONE WAVE PER NODE, pinned VGPR budget ----------------
// __launch_bounds__(256, 4): min 4 waves/EU -> 128-VGPR budget. Round 7/8 showed the
// default heuristic picks 40 VGPR and spills this loop (80MB scratch write-back);
// 4 waves/EU matches the measured ~48% occupancy so no TLP is lost.
// Lane owns 8 channels (c0 = lane*8), head = lane>>4. Per edge: broadcast csr load +
// per-head-group alpha load + 2 float4 h loads. 4-edge named unroll.
// POOL=1: layer-3 variant accumulates per-graph sums atomically.
template <int POOL>
__global__ void __launch_bounds__(256, 4) k_gather(
    const float* __restrict__ h, const float* __restrict__ ealpha,
    const float* __restrict__ invd, const int* __restrict__ row_start,
    const int* __restrict__ csr_src, const float* __restrict__ bias,
    float* __restrict__ xout, const int* __restrict__ batch,
    float* __restrict__ gsums) {
  int wid = threadIdx.x >> 6;
  int lane = threadIdx.x & 63;
  int n = blockIdx.x * 4 + wid;          // NN % 4 == 0, wave-uniform, no barriers
  int start = row_start[n];
  int deg = row_start[n + 1] - start;
  int head = lane >> 4;
  int c0 = lane * 8;
  const int* sp = csr_src + start;
  const float* ap = ealpha + (size_t)start * 4 + head;
  float4 accA = make_float4(0.f, 0.f, 0.f, 0.f);
  float4 accB = make_float4(0.f, 0.f, 0.f, 0.f);
  int j = 0;
  for (; j + 4 <= deg; j += 4) {
    int s0 = sp[j + 0], s1 = sp[j + 1], s2 = sp[j + 2], s3 = sp[j + 3];
    float a0 = ap[(j + 0) * 4], a1 = ap[(j + 1) * 4];
    float a2 = ap[(j + 2) * 4], a3 = ap[(j + 3) * 4];
    const float4* p0 = reinterpret_cast<const float4*>(&h[(size_t)s0 * OUTC + c0]);
    const float4* p1 = reinterpret_cast<const float4*>(&h[(size_t)s1 * OUTC + c0]);
    const float4* p2 = reinterpret_cast<const float4*>(&h[(size_t)s2 * OUTC + c0]);
    const float4* p3 = reinterpret_cast<const float4*>(&h[(size_t)s3 * OUTC + c0]);
    float4 h0a = p0[0], h0b = p0[1];
    float4 h1a = p1[0], h1b = p1[1];
    float4 h2a = p2[0], h2b = p2[1];
    float4 h3a = p3[0], h3b = p3[1];
    accA.x += a0 * h0a.x; accA.y += a0 * h0a.y; accA.z += a0 * h0a.z; accA.w += a0 * h0a.w;
    accB.x += a0 * h0b.x; accB.y += a0 * h0b.y; accB.z += a0 * h0b.z; accB.w += a0 * h0b.w;
    accA.x += a1 * h1a.x; accA.y += a1 * h1a.y; accA.z += a1 * h1a.z; accA.w += a1 * h1a.w;
    accB.x += a1 * h1b.x; accB.y += a1 * h1b.y; accB.z += a1 * h1b.z; accB.w += a1 * h1b.w;
    accA.x += a2 * h2a.x; accA.y += a2 * h2a.y; accA.z += a2 * h2a.z; accA.w += a2 * h2a.w;
    accB.x += a2 * h2b.x; accB.y += a2 * h2b.y; accB.z += a2 * h2b.z; accB.w += a2 * h2b.w;
    accA.x += a3 * h3a.x; accA.y += a3 * h3a.y; accA.z += a3 * h3a.z; accA.w += a3 * h3a.w;
    accB.x += a3 * h3b.x; accB.y += a3 * h3b.y; accB.z += a3 * h3b.z; accB.w += a3 * h3b.w;
  }
  for (; j < deg; ++j) {
    int sj = sp[j];
    float a = ap[j * 4];
    const float4* p = reinterpret_cast<const float4*>(&h[(size_t)sj * OUTC + c0]);
    float4 ha = p[0], hb = p[1];
    accA.x += a * ha.x; accA.y += a * ha.y; accA.z += a * ha.z; accA.w += a * ha.w;
    accB.x += a * hb.x; accB.y += a * hb.y; accB.z += a * hb.z; accB.w += a * hb.w;
  }
  // normalize (invd carries the 0.25 head-mean factor)
  float4 iv4 = *reinterpret_cast<const float4*>(&invd[(size_t)n * 4]);
  float myinv = (head == 0) ? iv4.x : (head == 1) ? iv4.y : (head == 2) ? iv4.z : iv4.w;
  accA.x *= myinv; accA.y *= myinv; accA.z *= myinv; accA.w *= myinv;
  accB.x *= myinv; accB.y *= myinv; accB.z *= myinv; accB.w *= myinv;
  // head-sum across lane groups: lanes l, l^16, l^32, l^48 hold same head-local channels
#pragma unroll
  for (int off = 16; off < 64; off <<= 1) {
    accA.x += __shfl_xor(accA.x, off); accA.y += __shfl_xor(accA.y, off);
    accA.z += __shfl_xor(accA.z, off); accA.w += __shfl_xor(accA.w, off);
    accB.x += __shfl_xor(accB.x, off); accB.y += __shfl_xor(accB.y, off);
    accB.z += __shfl_xor(accB.z, off); accB.w += __shfl_xor(accB.w, off);
  }
  if (lane < 16) {
    int cc = lane * 8;
    float4 b0 = *reinterpret_cast<const float4*>(&bias[cc]);
    float4 b1 = *reinterpret_cast<const float4*>(&bias[cc + 4]);
    float4 o0, o1;
    o0.x = fmaxf(accA.x + b0.x, 0.f);
    o0.y = fmaxf(accA.y + b0.y, 0.f);
    o0.z = fmaxf(accA.z + b0.z, 0.f);
    o0.w = fmaxf(accA.w + b0.w, 0.f);
    o1.x = fmaxf(accB.x + b1.x, 0.f);
    o1.y = fmaxf(accB.y + b1.y, 0.f);
    o1.z = fmaxf(accB.z + b1.z, 0.f);
    o1.w = fmaxf(accB.w + b1.w, 0.f);
    if (POOL) {
      int g = batch[n];
      float* gp = &gsums[(size_t)g * HID + cc];
      atomicAdd(&gp[0], o0.x); atomicAdd(&gp[1], o0.y);
      atomicAdd(&gp[2], o0.z); atomicAdd(&gp[3], o0.w);
      atomicAdd(&gp[4], o1.x); atomicAdd(&gp[5], o1.y);
      atomicAdd(&gp[6], o1.z); atomicAdd(&gp[7], o1.w);
    } else {
      *reinterpret_cast<float4*>(&xout[(size_t)n * HID + cc]) = o0;
      *reinterpret_cast<float4*>(&xout[(size_t)n * HID + cc + 4]) = o1;
    }
  }
}

// ---------------- MLP head (counts via binary search over sorted batch) ----------------
__global__ void k_mlp(const float* __restrict__ sums, const int* __restrict__ batch,
                      const float* __restrict__ bst, const float* __restrict__ M1,
                      const float* __restrict__ mb1, const float* __restrict__ M2,
                      const float* __restrict__ mb2, const float* __restrict__ M3,
                      const float* __restrict__ mb3, float* __restrict__ out) {
  int g = blockIdx.x, tid = threadIdx.x;  // 128 threads
  int lo = 0, hi = NN;
  while (lo < hi) { int mid = (lo + hi) >> 1; if (batch[mid] < g) lo = mid + 1; else hi = mid; }
  int s = lo;
  lo = s; hi = NN;
  while (lo < hi) { int mid = (lo + hi) >> 1; if (batch[mid] < g + 1) lo = mid + 1; else hi = mid; }
  int e = lo;
  float cnt = (float)(e - s);
  float pooled = sums[g * HID + tid] / fmaxf(cnt, 1.f);
  __shared__ float z[HID + 1];
  __shared__ float z1[HID];
  __shared__ float z2[64];
  z[tid] = pooled;
  if (tid == 0) z[HID] = log1pf(bst[g]);
  __syncthreads();
  float a1 = mb1[tid];
  for (int k = 0; k < HID + 1; ++k) a1 += z[k] * M1[k * HID + tid];
  z1[tid] = a1 > 0.f ? a1 : 0.f;
  __syncthreads();
  if (tid < 64) {
    float a2 = mb2[tid];
    for (int k = 0; k < HID; ++k) a2 += z1[k] * M2[k * 64 + tid];
    z2[tid] = a2 > 0.f ? a2 : 0.f;
  }
  __syncthreads();
  if (tid < 2) {
    float a3 = mb3[tid];
    for (int k = 0; k < 64; ++k) a3 += z2[k] * M3[k * 2 + tid];
    out[g * 2 + tid] = a3;
  }
}

extern "C" void kernel_launch(void* const* d_in, const int* in_sizes, int n_in,
                              void* d_out, int out_size, void* d_ws, size_t ws_size,
                              hipStream_t stream) {
  const float* x   = (const float*)d_in[0];
  const int*   ei  = (const int*)d_in[1];
  const int*   bat = (const int*)d_in[2];
  const float* bst = (const float*)d_in[3];
  const float* W1 = (const float*)d_in[4];
  const float* as1 = (const float*)d_in[5];
  const float* ad1 = (const float*)d_in[6];
  const float* b1 = (const float*)d_in[7];
  const float* W2 = (const float*)d_in[8];
  const float* as2 = (const float*)d_in[9];
  const float* ad2 = (const float*)d_in[10];
  const float* b2 = (const float*)d_in[11];
  const float* W3 = (const float*)d_in[12];
  const float* as3 = (const float*)d_in[13];
  const float* ad3 = (const float*)d_in[14];
  const float* b3 = (const float*)d_in[15];
  const float* M1 = (const float*)d_in[16];
  const float* mb1 = (const float*)d_in[17];
  const float* M2 = (const float*)d_in[18];
  const float* mb2 = (const float*)d_in[19];
  const float* M3 = (const float*)d_in[20];
  const float* mb3 = (const float*)d_in[21];
  float* out = (float*)d_out;

  char* ws = (char*)d_ws;
  auto alloc = [&](size_t bytes) -> void* {
    void* p = (void*)ws;
    ws += (bytes + 255) & ~(size_t)255;
    return p;
  };
  float* h_buf  = (float*)alloc((size_t)NN * OUTC * 4);
  float* x_buf  = (float*)alloc((size_t)NN * HID * 4);
  float* e_src  = (float*)alloc((size_t)NN * 4 * 4);
  float* e_dst  = (float*)alloc((size_t)NN * 4 * 4);
  int*   deg    = (int*)alloc((size_t)NN * 4);
  int*   rowst  = (int*)alloc((size_t)(NN + 1) * 4);
  int*   cursor = (int*)alloc((size_t)NN * 4);
  int*   csr    = (int*)alloc((size_t)ET * 4);
  float* ealpha = (float*)alloc((size_t)ET * 4 * 4);
  float* invd   = (float*)alloc((size_t)NN * 4 * 4);
  float* gsums  = (float*)alloc((size_t)NG * HID * 4);

  // CSR by destination
  hipMemsetAsync(deg, 0, (size_t)NN * 4, stream);
  hipMemsetAsync(gsums, 0, (size_t)NG * HID * 4, stream);
  k_hist<<<(ET + 255) / 256, 256, 0, stream>>>(ei, deg);
  k_scan<<<1, 1024, 0, stream>>>(deg, rowst, cursor);
  k_scatter<<<(ET + 255) / 256, 256, 0, stream>>>(ei, cursor, csr);

  dim3 ggrid(OUTC / 64, (NN + 63) / 64);
  dim3 pgrid(NN / 4);
  dim3 agrid(NN / 4);
  // layer 1
  k_gemm_t<12, 12><<<ggrid, 256, 0, stream>>>(x, W1, h_buf);
  k_esd<<<NN, 128, 0, stream>>>(h_buf, as1, ad1, e_src, e_dst);
  k_prep<<<pgrid, 256, 0, stream>>>(e_src, e_dst, rowst, csr, ealpha, invd);
  k_gather<0><<<agrid, 256, 0, stream>>>(h_buf, ealpha, invd, rowst, csr, b1, x_buf, bat, gsums);
  // layer 2
  k_gemm_t<128, 64><<<ggrid, 256, 0, stream>>>(x_buf, W2, h_buf);
  k_esd<<<NN, 128, 0, stream>>>(h_buf, as2, ad2, e_src, e_dst);
  k_prep<<<pgrid, 256, 0, stream>>>(e_src, e_dst, rowst, csr, ealpha, invd);
  k_gather<0><<<agrid, 256, 0, stream>>>(h_buf, ealpha, invd, rowst, csr, b2, x_buf, bat, gsums);
  // layer 3 (pool fused via atomics into gsums)
  k_gemm_t<128, 64><<<ggrid, 256, 0, stream>>>(x_buf, W3, h_buf);
  k_esd<<<NN, 128, 0, stream>>>(h_buf, as3, ad3, e_src, e_dst);
  k_prep<<<pgrid, 256, 0, stream>>>(e_src, e_dst, rowst, csr, ealpha, invd);
  k_gather<1><<<agrid, 256, 0, stream>>>(h_buf, ealpha, invd, rowst, csr, b3, x_buf, bat, gsums);
  // MLP head
  k_mlp<<<NG, 128, 0, stream>>>(gsums, bat, bst, M1, mb1, M2, mb2, M3, mb3, out);
}

// Round 10
// 541.307 us; speedup vs baseline: 1.3117x; 1.3035x over previous
//
#include <hip/hip_runtime.h>
#include <hip/hip_bf16.h>
#include <math.h>

#define NN 20000          // nodes
#define NE 320000         // edges (without self loops)
#define ET (NE + NN)      // edges + self loops
#define NG 64             // graphs
#define HEADS 4
#define HID 128
#define OUTC (HEADS * HID)   // 512
#define SLOPE 0.2f
#define NINF (-1e30f)

__device__ __forceinline__ float lrelu(float v) { return v > 0.f ? v : SLOPE * v; }

// ---------------- CSR build ----------------
__global__ void k_hist(const int* __restrict__ ei, int* __restrict__ deg) {
  int e = blockIdx.x * blockDim.x + threadIdx.x;
  if (e >= ET) return;
  int dst = (e < NE) ? ei[NE + e] : (e - NE);
  atomicAdd(&deg[dst], 1);
}

__global__ void k_scan(const int* __restrict__ deg, int* __restrict__ row_start,
                       int* __restrict__ cursor) {
  __shared__ int sums[1024];
  int tid = threadIdx.x;
  const int PER = (NN + 1023) / 1024;   // 20
  int base = tid * PER;
  int local = 0;
  for (int i = 0; i < PER; ++i) { int idx = base + i; if (idx < NN) local += deg[idx]; }
  sums[tid] = local;
  __syncthreads();
  for (int off = 1; off < 1024; off <<= 1) {
    int v = (tid >= off) ? sums[tid - off] : 0;
    __syncthreads();
    sums[tid] += v;
    __syncthreads();
  }
  int run = sums[tid] - local;  // exclusive prefix
  for (int i = 0; i < PER; ++i) {
    int idx = base + i;
    if (idx < NN) { row_start[idx] = run; cursor[idx] = run; run += deg[idx]; }
  }
  if (tid == 1023) row_start[NN] = sums[1023];
}

__global__ void k_scatter(const int* __restrict__ ei, int* __restrict__ cursor,
                          int* __restrict__ csr_src) {
  int e = blockIdx.x * blockDim.x + threadIdx.x;
  if (e >= ET) return;
  int src, dst;
  if (e < NE) { src = ei[e]; dst = ei[NE + e]; }
  else        { src = e - NE; dst = src; }
  int pos = atomicAdd(&cursor[dst], 1);
  csr_src[pos] = src;
}

// ---------------- tiled GEMM: h = x @ W,  x [NN,K], W [K,512] ----------------
template <int K, int BK>
__global__ void k_gemm_t(const float* __restrict__ x, const float* __restrict__ W,
                         float* __restrict__ h) {
  const int BM = 64, BN = 64;
  __shared__ float sAT[BK][BM + 4];
  __shared__ float sB[BK][BN];
  int tid = threadIdx.x;
  int r0 = blockIdx.y * BM;
  int cb = blockIdx.x * BN;
  int tx = tid & 15, ty = tid >> 4;
  int m0 = ty * 4, n0 = tx * 4;
  float acc[4][4] = {};
  for (int k0 = 0; k0 < K; k0 += BK) {
    const int AF4 = BM * BK / 4;
    for (int idx = tid; idx < AF4; idx += 256) {
      int r = idx / (BK / 4);
      int kq = idx % (BK / 4);
      int row = r0 + r;
      float4 v = make_float4(0.f, 0.f, 0.f, 0.f);
      if (row < NN) v = *reinterpret_cast<const float4*>(&x[(size_t)row * K + k0 + kq * 4]);
      sAT[kq * 4 + 0][r] = v.x;
      sAT[kq * 4 + 1][r] = v.y;
      sAT[kq * 4 + 2][r] = v.z;
      sAT[kq * 4 + 3][r] = v.w;
    }
    const int BF4 = BK * BN / 4;
    for (int idx = tid; idx < BF4; idx += 256) {
      int k = idx / 16, nq = idx & 15;
      float4 v = *reinterpret_cast<const float4*>(&W[(size_t)(k0 + k) * OUTC + cb + nq * 4]);
      *reinterpret_cast<float4*>(&sB[k][nq * 4]) = v;
    }
    __syncthreads();
#pragma unroll 4
    for (int kk = 0; kk < BK; ++kk) {
      float4 a = *reinterpret_cast<const float4*>(&sAT[kk][m0]);
      float4 b = *reinterpret_cast<const float4*>(&sB[kk][n0]);
      acc[0][0] += a.x * b.x; acc[0][1] += a.x * b.y; acc[0][2] += a.x * b.z; acc[0][3] += a.x * b.w;
      acc[1][0] += a.y * b.x; acc[1][1] += a.y * b.y; acc[1][2] += a.y * b.z; acc[1][3] += a.y * b.w;
      acc[2][0] += a.z * b.x; acc[2][1] += a.z * b.y; acc[2][2] += a.z * b.z; acc[2][3] += a.z * b.w;
      acc[3][0] += a.w * b.x; acc[3][1] += a.w * b.y; acc[3][2] += a.w * b.z; acc[3][3] += a.w * b.w;
    }
    __syncthreads();
  }
#pragma unroll
  for (int i = 0; i < 4; ++i) {
    int row = r0 + m0 + i;
    if (row < NN) {
      float4 v = make_float4(acc[i][0], acc[i][1], acc[i][2], acc[i][3]);
      *reinterpret_cast<float4*>(&h[(size_t)row * OUTC + cb + n0]) = v;
    }
  }
}

// ---------------- attention logits per node (float4, 128 thr/node) ----------------
__global__ void k_esd(const float* __restrict__ h, const float* __restrict__ as,
                      const float* __restrict__ ad, float* __restrict__ e_src,
                      float* __restrict__ e_dst) {
  int n = blockIdx.x;
  int tid = threadIdx.x;       // 128
  int head = tid >> 5, q = tid & 31;
  float4 hv = *reinterpret_cast<const float4*>(&h[(size_t)n * OUTC + head * HID + q * 4]);
  float4 av = *reinterpret_cast<const float4*>(&as[head * HID + q * 4]);
  float4 dv = *reinterpret_cast<const float4*>(&ad[head * HID + q * 4]);
  float ps = hv.x * av.x + hv.y * av.y + hv.z * av.z + hv.w * av.w;
  float pd = hv.x * dv.x + hv.y * dv.y + hv.z * dv.z + hv.w * dv.w;
#pragma unroll
  for (int off = 1; off < 32; off <<= 1) {
    ps += __shfl_xor(ps, off);
    pd += __shfl_xor(pd, off);
  }
  if (q == 0) { e_src[n * HEADS + head] = ps; e_dst[n * HEADS + head] = pd; }
}

// ---------------- edge-softmax prep: one wave per node ----------------
__global__ void __launch_bounds__(256) k_prep(
    const float* __restrict__ es, const float* __restrict__ ed,
    const int* __restrict__ row_start, const int* __restrict__ csr_src,
    float* __restrict__ ealpha, float* __restrict__ invd) {
  int wid = threadIdx.x >> 6;
  int lane = threadIdx.x & 63;
  int n = blockIdx.x * 4 + wid;          // NN % 4 == 0
  int start = row_start[n];
  int deg = row_start[n + 1] - start;
  float4 edv = *reinterpret_cast<const float4*>(&ed[(size_t)n * 4]);
  // pass 1: per-head max
  float m0 = NINF, m1 = NINF, m2 = NINF, m3 = NINF;
  for (int k = lane; k < deg; k += 64) {
    int s = csr_src[start + k];
    float4 e4 = *reinterpret_cast<const float4*>(&es[(size_t)s * 4]);
    m0 = fmaxf(m0, lrelu(e4.x + edv.x));
    m1 = fmaxf(m1, lrelu(e4.y + edv.y));
    m2 = fmaxf(m2, lrelu(e4.z + edv.z));
    m3 = fmaxf(m3, lrelu(e4.w + edv.w));
  }
#pragma unroll
  for (int off = 1; off < 64; off <<= 1) {
    m0 = fmaxf(m0, __shfl_xor(m0, off));
    m1 = fmaxf(m1, __shfl_xor(m1, off));
    m2 = fmaxf(m2, __shfl_xor(m2, off));
    m3 = fmaxf(m3, __shfl_xor(m3, off));
  }
  // pass 2: exp numerators -> ealpha (coalesced float4 store), accumulate denom
  float d0 = 0.f, d1 = 0.f, d2 = 0.f, d3 = 0.f;
  for (int k = lane; k < deg; k += 64) {
    int s = csr_src[start + k];
    float4 e4 = *reinterpret_cast<const float4*>(&es[(size_t)s * 4]);
    float4 ex;
    ex.x = __expf(lrelu(e4.x + edv.x) - m0);
    ex.y = __expf(lrelu(e4.y + edv.y) - m1);
    ex.z = __expf(lrelu(e4.z + edv.z) - m2);
    ex.w = __expf(lrelu(e4.w + edv.w) - m3);
    *reinterpret_cast<float4*>(&ealpha[(size_t)(start + k) * 4]) = ex;
    d0 += ex.x; d1 += ex.y; d2 += ex.z; d3 += ex.w;
  }
#pragma unroll
  for (int off = 1; off < 64; off <<= 1) {
    d0 += __shfl_xor(d0, off);
    d1 += __shfl_xor(d1, off);
    d2 += __shfl_xor(d2, off);
    d3 += __shfl_xor(d3, off);
  }
  if (lane == 0) {
    float4 iv;
    iv.x = 0.25f / d0; iv.y = 0.25f / d1; iv.z = 0.25f / d2; iv.w = 0.25f / d3;
    *reinterpret_cast<float4*>(&invd[(size_t)n * 4]) = iv;
  }
}

// ---------------- weighted gather: BLOCK PER NODE, float2 per thread ----------------
// 256 threads = full 512-channel h row per edge (fully coalesced 2KB).
// Metadata (csr_src, ealpha) loads are block/wave-uniform -> scalar loads (SGPR),
// so the per-edge vector live set is just one float2 -> ~30 VGPR, nothing to spill
// (r4-r9 lesson: any large per-lane live set gets spilled at the allocator's whim).
// 8-deep unroll = 8 outstanding 8B loads/thread. POOL=1: atomicAdd per-graph sums.
template <int POOL>
__global__ void __launch_bounds__(256, 4) k_gather(
    const float* __restrict__ h, const float* __restrict__ ealpha,
    const float* __restrict__ invd, const int* __restrict__ row_start,
    const int* __restrict__ csr_src, const float* __restrict__ bias,
    float* __restrict__ xout, const int* __restrict__ batch,
    float* __restrict__ gsums) {
  __shared__ float xs[OUTC];
  int n = blockIdx.x;
  int tid = threadIdx.x;                  // 256
  int start = row_start[n];
  int deg = row_start[n + 1] - start;
  int head = __builtin_amdgcn_readfirstlane(tid >> 6);  // wave-uniform -> SGPR
  int c = tid * 2;
  const int* sp = csr_src + start;
  const float* ap = ealpha + (size_t)start * 4 + head;  // uniform pointer -> s_load
  float ax = 0.f, ay = 0.f;
  int j = 0;
  for (; j + 8 <= deg; j += 8) {
    int s0 = sp[j + 0], s1 = sp[j + 1], s2 = sp[j + 2], s3 = sp[j + 3];
    int s4 = sp[j + 4], s5 = sp[j + 5], s6 = sp[j + 6], s7 = sp[j + 7];
    float a0 = ap[(j + 0) * 4], a1 = ap[(j + 1) * 4];
    float a2 = ap[(j + 2) * 4], a3 = ap[(j + 3) * 4];
    float a4 = ap[(j + 4) * 4], a5 = ap[(j + 5) * 4];
    float a6 = ap[(j + 6) * 4], a7 = ap[(j + 7) * 4];
    float2 h0 = *reinterpret_cast<const float2*>(&h[(size_t)s0 * OUTC + c]);
    float2 h1 = *reinterpret_cast<const float2*>(&h[(size_t)s1 * OUTC + c]);
    float2 h2 = *reinterpret_cast<const float2*>(&h[(size_t)s2 * OUTC + c]);
    float2 h3 = *reinterpret_cast<const float2*>(&h[(size_t)s3 * OUTC + c]);
    float2 h4 = *reinterpret_cast<const float2*>(&h[(size_t)s4 * OUTC + c]);
    float2 h5 = *reinterpret_cast<const float2*>(&h[(size_t)s5 * OUTC + c]);
    float2 h6 = *reinterpret_cast<const float2*>(&h[(size_t)s6 * OUTC + c]);
    float2 h7 = *reinterpret_cast<const float2*>(&h[(size_t)s7 * OUTC + c]);
    ax += a0 * h0.x; ay += a0 * h0.y;
    ax += a1 * h1.x; ay += a1 * h1.y;
    ax += a2 * h2.x; ay += a2 * h2.y;
    ax += a3 * h3.x; ay += a3 * h3.y;
    ax += a4 * h4.x; ay += a4 * h4.y;
    ax += a5 * h5.x; ay += a5 * h5.y;
    ax += a6 * h6.x; ay += a6 * h6.y;
    ax += a7 * h7.x; ay += a7 * h7.y;
  }
  for (; j < deg; ++j) {
    int sj = sp[j];
    float a = ap[j * 4];
    float2 hv = *reinterpret_cast<const float2*>(&h[(size_t)sj * OUTC + c]);
    ax += a * hv.x; ay += a * hv.y;
  }
  // normalize (invd carries the 0.25 head-mean factor); uniform load
  float myinv = invd[(size_t)n * 4 + head];
  ax *= myinv; ay *= myinv;
  // head-mean via LDS
  *reinterpret_cast<float2*>(&xs[c]) = make_float2(ax, ay);
  __syncthreads();
  if (tid < HID) {
    float o = xs[tid] + xs[HID + tid] + xs[2 * HID + tid] + xs[3 * HID + tid] + bias[tid];
    o = fmaxf(o, 0.f);
    if (POOL) {
      atomicAdd(&gsums[(size_t)batch[n] * HID + tid], o);
    } else {
      xout[(size_t)n * HID + tid] = o;
    }
  }
}

// ---------------- MLP head (counts via binary search over sorted batch) ----------------
__global__ void k_mlp(const float* __restrict__ sums, const int* __restrict__ batch,
                      const float* __restrict__ bst, const float* __restrict__ M1,
                      const float* __restrict__ mb1, const float* __restrict__ M2,
                      const float* __restrict__ mb2, const float* __restrict__ M3,
                      const float* __restrict__ mb3, float* __restrict__ out) {
  int g = blockIdx.x, tid = threadIdx.x;  // 128 threads
  int lo = 0, hi = NN;
  while (lo < hi) { int mid = (lo + hi) >> 1; if (batch[mid] < g) lo = mid + 1; else hi = mid; }
  int s = lo;
  lo = s; hi = NN;
  while (lo < hi) { int mid = (lo + hi) >> 1; if (batch[mid] < g + 1) lo = mid + 1; else hi = mid; }
  int e = lo;
  float cnt = (float)(e - s);
  float pooled = sums[g * HID + tid] / fmaxf(cnt, 1.f);
  __shared__ float z[HID + 1];
  __shared__ float z1[HID];
  __shared__ float z2[64];
  z[tid] = pooled;
  if (tid == 0) z[HID] = log1pf(bst[g]);
  __syncthreads();
  float a1 = mb1[tid];
  for (int k = 0; k < HID + 1; ++k) a1 += z[k] * M1[k * HID + tid];
  z1[tid] = a1 > 0.f ? a1 : 0.f;
  __syncthreads();
  if (tid < 64) {
    float a2 = mb2[tid];
    for (int k = 0; k < HID; ++k) a2 += z1[k] * M2[k * 64 + tid];
    z2[tid] = a2 > 0.f ? a2 : 0.f;
  }
  __syncthreads();
  if (tid < 2) {
    float a3 = mb3[tid];
    for (int k = 0; k < 64; ++k) a3 += z2[k] * M3[k * 2 + tid];
    out[g * 2 + tid] = a3;
  }
}

extern "C" void kernel_launch(void* const* d_in, const int* in_sizes, int n_in,
                              void* d_out, int out_size, void* d_ws, size_t ws_size,
                              hipStream_t stream) {
  const float* x   = (const float*)d_in[0];
  const int*   ei  = (const int*)d_in[1];
  const int*   bat = (const int*)d_in[2];
  const float* bst = (const float*)d_in[3];
  const float* W1 = (const float*)d_in[4];
  const float* as1 = (const float*)d_in[5];
  const float* ad1 = (const float*)d_in[6];
  const float* b1 = (const float*)d_in[7];
  const float* W2 = (const float*)d_in[8];
  const float* as2 = (const float*)d_in[9];
  const float* ad2 = (const float*)d_in[10];
  const float* b2 = (const float*)d_in[11];
  const float* W3 = (const float*)d_in[12];
  const float* as3 = (const float*)d_in[13];
  const float* ad3 = (const float*)d_in[14];
  const float* b3 = (const float*)d_in[15];
  const float* M1 = (const float*)d_in[16];
  const float* mb1 = (const float*)d_in[17];
  const float* M2 = (const float*)d_in[18];
  const float* mb2 = (const float*)d_in[19];
  const float* M3 = (const float*)d_in[20];
  const float* mb3 = (const float*)d_in[21];
  float* out = (float*)d_out;

  char* ws = (char*)d_ws;
  auto alloc = [&](size_t bytes) -> void* {
    void* p = (void*)ws;
    ws += (bytes + 255) & ~(size_t)255;
    return p;
  };
  float* h_buf  = (float*)alloc((size_t)NN * OUTC * 4);
  float* x_buf  = (float*)alloc((size_t)NN * HID * 4);
  float* e_src  = (float*)alloc((size_t)NN * 4 * 4);
  float* e_dst  = (float*)alloc((size_t)NN * 4 * 4);
  int*   deg    = (int*)alloc((size_t)NN * 4);
  int*   rowst  = (int*)alloc((size_t)(NN + 1) * 4);
  int*   cursor = (int*)alloc((size_t)NN * 4);
  int*   csr    = (int*)alloc((size_t)ET * 4);
  float* ealpha = (float*)alloc((size_t)ET * 4 * 4);
  float* invd   = (float*)alloc((size_t)NN * 4 * 4);
  float* gsums  = (float*)alloc((size_t)NG * HID * 4);

  // CSR by destination
  hipMemsetAsync(deg, 0, (size_t)NN * 4, stream);
  hipMemsetAsync(gsums, 0, (size_t)NG * HID * 4, stream);
  k_hist<<<(ET + 255) / 256, 256, 0, stream>>>(ei, deg);
  k_scan<<<1, 1024, 0, stream>>>(deg, rowst, cursor);
  k_scatter<<<(ET + 255) / 256, 256, 0, stream>>>(ei, cursor, csr);

  dim3 ggrid(OUTC / 64, (NN + 63) / 64);
  dim3 pgrid(NN / 4);
  // layer 1
  k_gemm_t<12, 12><<<ggrid, 256, 0, stream>>>(x, W1, h_buf);
  k_esd<<<NN, 128, 0, stream>>>(h_buf, as1, ad1, e_src, e_dst);
  k_prep<<<pgrid, 256, 0, stream>>>(e_src, e_dst, rowst, csr, ealpha, invd);
  k_gather<0><<<NN, 256, 0, stream>>>(h_buf, ealpha, invd, rowst, csr, b1, x_buf, bat, gsums);
  // layer 2
  k_gemm_t<128, 64><<<ggrid, 256, 0, stream>>>(x_buf, W2, h_buf);
  k_esd<<<NN, 128, 0, stream>>>(h_buf, as2, ad2, e_src, e_dst);
  k_prep<<<pgrid, 256, 0, stream>>>(e_src, e_dst, rowst, csr, ealpha, invd);
  k_gather<0><<<NN, 256, 0, stream>>>(h_buf, ealpha, invd, rowst, csr, b2, x_buf, bat, gsums);
  // layer 3 (pool fused via atomics into gsums)
  k_gemm_t<128, 64><<<ggrid, 256, 0, stream>>>(x_buf, W3, h_buf);
  k_esd<<<NN, 128, 0, stream>>>(h_buf, as3, ad3, e_src, e_dst);
  k_prep<<<pgrid, 256, 0, stream>>>(e_src, e_dst, rowst, csr, ealpha, invd);
  k_gather<1><<<NN, 256, 0, stream>>>(h_buf, ealpha, invd, rowst, csr, b3, x_buf, bat, gsums);
  // MLP head
  k_mlp<<<NG, 128, 0, stream>>>(gsums, bat, bst, M1, mb1, M2, mb2, M3, mb3, out);
}

// Round 11
// 455.312 us; speedup vs baseline: 1.5594x; 1.1889x over previous
//
#include <hip/hip_runtime.h>
#include <hip/hip_bf16.h>
#include <math.h>

#define NN 20000          // nodes
#define NE 320000         // edges (without self loops)
#define ET (NE + NN)      // edges + self loops
#define NG 64             // graphs
#define HEADS 4
#define HID 128
#define OUTC (HEADS * HID)   // 512
#define SLOPE 0.2f
#define NINF (-1e30f)

__device__ __forceinline__ float lrelu(float v) { return v > 0.f ? v : SLOPE * v; }

// ---------------- CSR build ----------------
__global__ void k_hist(const int* __restrict__ ei, int* __restrict__ deg) {
  int e = blockIdx.x * blockDim.x + threadIdx.x;
  if (e >= ET) return;
  int dst = (e < NE) ? ei[NE + e] : (e - NE);
  atomicAdd(&deg[dst], 1);
}

__global__ void k_scan(const int* __restrict__ deg, int* __restrict__ row_start,
                       int* __restrict__ cursor) {
  __shared__ int sums[1024];
  int tid = threadIdx.x;
  const int PER = (NN + 1023) / 1024;   // 20
  int base = tid * PER;
  int local = 0;
  for (int i = 0; i < PER; ++i) { int idx = base + i; if (idx < NN) local += deg[idx]; }
  sums[tid] = local;
  __syncthreads();
  for (int off = 1; off < 1024; off <<= 1) {
    int v = (tid >= off) ? sums[tid - off] : 0;
    __syncthreads();
    sums[tid] += v;
    __syncthreads();
  }
  int run = sums[tid] - local;  // exclusive prefix
  for (int i = 0; i < PER; ++i) {
    int idx = base + i;
    if (idx < NN) { row_start[idx] = run; cursor[idx] = run; run += deg[idx]; }
  }
  if (tid == 1023) row_start[NN] = sums[1023];
}

__global__ void k_scatter(const int* __restrict__ ei, int* __restrict__ cursor,
                          int* __restrict__ csr_src) {
  int e = blockIdx.x * blockDim.x + threadIdx.x;
  if (e >= ET) return;
  int src, dst;
  if (e < NE) { src = ei[e]; dst = ei[NE + e]; }
  else        { src = e - NE; dst = src; }
  int pos = atomicAdd(&cursor[dst], 1);
  csr_src[pos] = src;
}

// ---------------- watt[k,t] = sum_c W[k, h*128+c] * a[h,c]  (t<4: as, t>=4: ad, h=t&3) ----
__global__ void k_watt(const float* __restrict__ W, const float* __restrict__ as,
                       const float* __restrict__ ad, float* __restrict__ watt) {
  int k = blockIdx.x;             // grid = K
  int tid = threadIdx.x;          // 256 = 32 c-chunks x 8 t
  int t = tid & 7, h = t & 3;
  int c0 = (tid >> 3) * 4;
  const float* av = (t < 4 ? as : ad) + h * HID;
  const float* wr = W + (size_t)k * OUTC + h * HID;
  float4 wv = *reinterpret_cast<const float4*>(&wr[c0]);
  float4 a4 = *reinterpret_cast<const float4*>(&av[c0]);
  float p = wv.x * a4.x + wv.y * a4.y + wv.z * a4.z + wv.w * a4.w;
  __shared__ float lp[32][8];
  lp[tid >> 3][t] = p;
  __syncthreads();
  if (tid < 8) {
    float s = 0.f;
    for (int cc = 0; cc < 32; ++cc) s += lp[cc][tid];
    watt[k * 8 + tid] = s;
  }
}

// ---------------- attention logits, K=12 (layer 1): thread per node ----------------
__global__ void k_esd1(const float* __restrict__ x, const float* __restrict__ watt,
                       float* __restrict__ es, float* __restrict__ ed) {
  int n = blockIdx.x * blockDim.x + threadIdx.x;
  if (n >= NN) return;
  float xr[12];
#pragma unroll
  for (int k = 0; k < 12; ++k) xr[k] = x[(size_t)n * 12 + k];
#pragma unroll
  for (int t = 0; t < 8; ++t) {
    float acc = 0.f;
#pragma unroll
    for (int k = 0; k < 12; ++k) acc += xr[k] * watt[k * 8 + t];
    if (t < 4) es[n * 4 + t] = acc;
    else       ed[n * 4 + (t - 4)] = acc;
  }
}

// ---------------- attention logits, K=128: wave per node (grid-stride), watt in LDS ----
__global__ void __launch_bounds__(256) k_esd128(
    const float* __restrict__ x, const float* __restrict__ watt,
    float* __restrict__ es, float* __restrict__ ed) {
  __shared__ float sw[HID * 8];
  int tid = threadIdx.x;
  for (int i = tid; i < HID * 8; i += 256) sw[i] = watt[i];
  __syncthreads();
  int wid = tid >> 6, lane = tid & 63;
  int gw = blockIdx.x * 4 + wid;
  int nw = gridDim.x * 4;
  for (int n = gw; n < NN; n += nw) {
    float2 xv = *reinterpret_cast<const float2*>(&x[(size_t)n * HID + lane * 2]);
    float p[8];
#pragma unroll
    for (int t = 0; t < 8; ++t)
      p[t] = xv.x * sw[(lane * 2) * 8 + t] + xv.y * sw[(lane * 2 + 1) * 8 + t];
#pragma unroll
    for (int t = 0; t < 8; ++t) {
#pragma unroll
      for (int off = 1; off < 64; off <<= 1) p[t] += __shfl_xor(p[t], off);
    }
    if (lane == 0) {
      es[n * 4 + 0] = p[0]; es[n * 4 + 1] = p[1];
      es[n * 4 + 2] = p[2]; es[n * 4 + 3] = p[3];
      ed[n * 4 + 0] = p[4]; ed[n * 4 + 1] = p[5];
      ed[n * 4 + 2] = p[6]; ed[n * 4 + 3] = p[7];
    }
  }
}

// ---------------- edge-softmax prep: one wave per node (unchanged, verified) ----------
__global__ void __launch_bounds__(256) k_prep(
    const float* __restrict__ es, const float* __restrict__ ed,
    const int* __restrict__ row_start, const int* __restrict__ csr_src,
    float* __restrict__ ealpha, float* __restrict__ invd) {
  int wid = threadIdx.x >> 6;
  int lane = threadIdx.x & 63;
  int n = blockIdx.x * 4 + wid;          // NN % 4 == 0
  int start = row_start[n];
  int deg = row_start[n + 1] - start;
  float4 edv = *reinterpret_cast<const float4*>(&ed[(size_t)n * 4]);
  float m0 = NINF, m1 = NINF, m2 = NINF, m3 = NINF;
  for (int k = lane; k < deg; k += 64) {
    int s = csr_src[start + k];
    float4 e4 = *reinterpret_cast<const float4*>(&es[(size_t)s * 4]);
    m0 = fmaxf(m0, lrelu(e4.x + edv.x));
    m1 = fmaxf(m1, lrelu(e4.y + edv.y));
    m2 = fmaxf(m2, lrelu(e4.z + edv.z));
    m3 = fmaxf(m3, lrelu(e4.w + edv.w));
  }
#pragma unroll
  for (int off = 1; off < 64; off <<= 1) {
    m0 = fmaxf(m0, __shfl_xor(m0, off));
    m1 = fmaxf(m1, __shfl_xor(m1, off));
    m2 = fmaxf(m2, __shfl_xor(m2, off));
    m3 = fmaxf(m3, __shfl_xor(m3, off));
  }
  float d0 = 0.f, d1 = 0.f, d2 = 0.f, d3 = 0.f;
  for (int k = lane; k < deg; k += 64) {
    int s = csr_src[start + k];
    float4 e4 = *reinterpret_cast<const float4*>(&es[(size_t)s * 4]);
    float4 ex;
    ex.x = __expf(lrelu(e4.x + edv.x) - m0);
    ex.y = __expf(lrelu(e4.y + edv.y) - m1);
    ex.z = __expf(lrelu(e4.z + edv.z) - m2);
    ex.w = __expf(lrelu(e4.w + edv.w) - m3);
    *reinterpret_cast<float4*>(&ealpha[(size_t)(start + k) * 4]) = ex;
    d0 += ex.x; d1 += ex.y; d2 += ex.z; d3 += ex.w;
  }
#pragma unroll
  for (int off = 1; off < 64; off <<= 1) {
    d0 += __shfl_xor(d0, off);
    d1 += __shfl_xor(d1, off);
    d2 += __shfl_xor(d2, off);
    d3 += __shfl_xor(d3, off);
  }
  if (lane == 0) {
    float4 iv;
    iv.x = 0.25f / d0; iv.y = 0.25f / d1; iv.z = 0.25f / d2; iv.w = 0.25f / d3;
    *reinterpret_cast<float4*>(&invd[(size_t)n * 4]) = iv;
  }
}

// ---------------- x-aggregation K=128: wave per node, lane owns 2 channels of x ------
// z[n, h*128+c] = invd[n,h] * sum_j alpha[j,h] * x[src_j, c].  Gathers 512B/edge
// (vs 2KB for h-gather) from a 10MB working set. alpha/src are wave-uniform s_loads;
// per-lane live set = 4 float2 acc + 4 in-flight float2 -> ~30 VGPR, no spill (r10 shape).
__global__ void __launch_bounds__(256, 4) k_aggx128(
    const float* __restrict__ x, const float* __restrict__ ealpha,
    const float* __restrict__ invd, const int* __restrict__ row_start,
    const int* __restrict__ csr_src, float* __restrict__ z) {
  int wid = threadIdx.x >> 6;
  int lane = threadIdx.x & 63;
  int n = blockIdx.x * 4 + wid;
  int start = row_start[n];
  int deg = row_start[n + 1] - start;
  const int* sp = csr_src + start;
  const float4* ap4 = reinterpret_cast<const float4*>(ealpha) + start;
  int c = lane * 2;
  float2 a0c = make_float2(0.f, 0.f), a1c = make_float2(0.f, 0.f);
  float2 a2c = make_float2(0.f, 0.f), a3c = make_float2(0.f, 0.f);
  int j = 0;
  for (; j + 4 <= deg; j += 4) {
    int s0 = sp[j + 0], s1 = sp[j + 1], s2 = sp[j + 2], s3 = sp[j + 3];
    float4 q0 = ap4[j + 0], q1 = ap4[j + 1], q2 = ap4[j + 2], q3 = ap4[j + 3];
    float2 x0 = *reinterpret_cast<const float2*>(&x[(size_t)s0 * HID + c]);
    float2 x1 = *reinterpret_cast<const float2*>(&x[(size_t)s1 * HID + c]);
    float2 x2 = *reinterpret_cast<const float2*>(&x[(size_t)s2 * HID + c]);
    float2 x3 = *reinterpret_cast<const float2*>(&x[(size_t)s3 * HID + c]);
    a0c.x += q0.x * x0.x; a0c.y += q0.x * x0.y;
    a1c.x += q0.y * x0.x; a1c.y += q0.y * x0.y;
    a2c.x += q0.z * x0.x; a2c.y += q0.z * x0.y;
    a3c.x += q0.w * x0.x; a3c.y += q0.w * x0.y;
    a0c.x += q1.x * x1.x; a0c.y += q1.x * x1.y;
    a1c.x += q1.y * x1.x; a1c.y += q1.y * x1.y;
    a2c.x += q1.z * x1.x; a2c.y += q1.z * x1.y;
    a3c.x += q1.w * x1.x; a3c.y += q1.w * x1.y;
    a0c.x += q2.x * x2.x; a0c.y += q2.x * x2.y;
    a1c.x += q2.y * x2.x; a1c.y += q2.y * x2.y;
    a2c.x += q2.z * x2.x; a2c.y += q2.z * x2.y;
    a3c.x += q2.w * x2.x; a3c.y += q2.w * x2.y;
    a0c.x += q3.x * x3.x; a0c.y += q3.x * x3.y;
    a1c.x += q3.y * x3.x; a1c.y += q3.y * x3.y;
    a2c.x += q3.z * x3.x; a2c.y += q3.z * x3.y;
    a3c.x += q3.w * x3.x; a3c.y += q3.w * x3.y;
  }
  for (; j < deg; ++j) {
    int s = sp[j];
    float4 q = ap4[j];
    float2 xv = *reinterpret_cast<const float2*>(&x[(size_t)s * HID + c]);
    a0c.x += q.x * xv.x; a0c.y += q.x * xv.y;
    a1c.x += q.y * xv.x; a1c.y += q.y * xv.y;
    a2c.x += q.z * xv.x; a2c.y += q.z * xv.y;
    a3c.x += q.w * xv.x; a3c.y += q.w * xv.y;
  }
  float4 iv = *reinterpret_cast<const float4*>(&invd[(size_t)n * 4]);
  a0c.x *= iv.x; a0c.y *= iv.x;
  a1c.x *= iv.y; a1c.y *= iv.y;
  a2c.x *= iv.z; a2c.y *= iv.z;
  a3c.x *= iv.w; a3c.y *= iv.w;
  float* zr = z + (size_t)n * OUTC;
  *reinterpret_cast<float2*>(&zr[0 * HID + c]) = a0c;
  *reinterpret_cast<float2*>(&zr[1 * HID + c]) = a1c;
  *reinterpret_cast<float2*>(&zr[2 * HID + c]) = a2c;
  *reinterpret_cast<float2*>(&zr[3 * HID + c]) = a3c;
}

// ---------------- x-aggregation K=12 (layer 1): wave per node ----------------
// lane = h*16 + c (c<12 active). z1[n, h*12+c] = invd[n,h] * sum_j alpha[j,h]*x[s_j,c].
__global__ void __launch_bounds__(256, 4) k_aggx1(
    const float* __restrict__ x, const float* __restrict__ ealpha,
    const float* __restrict__ invd, const int* __restrict__ row_start,
    const int* __restrict__ csr_src, float* __restrict__ z1) {
  int wid = threadIdx.x >> 6;
  int lane = threadIdx.x & 63;
  int n = blockIdx.x * 4 + wid;
  int start = row_start[n];
  int deg = row_start[n + 1] - start;
  const int* sp = csr_src + start;
  const float4* ap4 = reinterpret_cast<const float4*>(ealpha) + start;
  int h = lane >> 4;
  int cr = lane & 15;
  int cc = cr < 12 ? cr : 11;    // clamp: lanes 12-15 compute garbage, never stored
  float acc = 0.f;
  int j = 0;
  for (; j + 4 <= deg; j += 4) {
    int s0 = sp[j + 0], s1 = sp[j + 1], s2 = sp[j + 2], s3 = sp[j + 3];
    float4 q0 = ap4[j + 0], q1 = ap4[j + 1], q2 = ap4[j + 2], q3 = ap4[j + 3];
    float ah0 = (h == 0) ? q0.x : (h == 1) ? q0.y : (h == 2) ? q0.z : q0.w;
    float ah1 = (h == 0) ? q1.x : (h == 1) ? q1.y : (h == 2) ? q1.z : q1.w;
    float ah2 = (h == 0) ? q2.x : (h == 1) ? q2.y : (h == 2) ? q2.z : q2.w;
    float ah3 = (h == 0) ? q3.x : (h == 1) ? q3.y : (h == 2) ? q3.z : q3.w;
    float x0 = x[(size_t)s0 * 12 + cc];
    float x1 = x[(size_t)s1 * 12 + cc];
    float x2 = x[(size_t)s2 * 12 + cc];
    float x3 = x[(size_t)s3 * 12 + cc];
    acc += ah0 * x0 + ah1 * x1 + ah2 * x2 + ah3 * x3;
  }
  for (; j < deg; ++j) {
    int s = sp[j];
    float4 q = ap4[j];
    float ah = (h == 0) ? q.x : (h == 1) ? q.y : (h == 2) ? q.z : q.w;
    acc += ah * x[(size_t)s * 12 + cc];
  }
  float ivh = invd[(size_t)n * 4 + h];
  if (cr < 12) z1[(size_t)n * 48 + h * 12 + cr] = acc * ivh;
}

// ---------------- GEMM: out = relu(z @ Wperm + b), Wperm[h*KH+k, c] = W[k, h*128+c] --
// KTOT = 4*KH. POOL=1: atomicAdd into per-graph sums instead of writing xout.
template <int KTOT, int KH, int BK, int POOL>
__global__ void k_gemm_z(const float* __restrict__ z, const float* __restrict__ W,
                         const float* __restrict__ bias, const int* __restrict__ batch,
                         float* __restrict__ xout, float* __restrict__ gsums) {
  const int BM = 64, BN = 64;
  __shared__ float sAT[BK][BM + 4];
  __shared__ float sB[BK][BN];
  int tid = threadIdx.x;
  int r0 = blockIdx.y * BM;
  int cb = blockIdx.x * BN;      // 0 or 64 (out is 128 wide)
  int tx = tid & 15, ty = tid >> 4;
  int m0 = ty * 4, n0 = tx * 4;
  float acc[4][4] = {};
  for (int k0 = 0; k0 < KTOT; k0 += BK) {
    const int AF4 = BM * BK / 4;
    for (int idx = tid; idx < AF4; idx += 256) {
      int r = idx / (BK / 4);
      int kq = idx % (BK / 4);
      int row = r0 + r;
      float4 v = make_float4(0.f, 0.f, 0.f, 0.f);
      if (row < NN) v = *reinterpret_cast<const float4*>(&z[(size_t)row * KTOT + k0 + kq * 4]);
      sAT[kq * 4 + 0][r] = v.x;
      sAT[kq * 4 + 1][r] = v.y;
      sAT[kq * 4 + 2][r] = v.z;
      sAT[kq * 4 + 3][r] = v.w;
    }
    const int BF4 = BK * BN / 4;
    for (int idx = tid; idx < BF4; idx += 256) {
      int kr = idx / 16, nq = idx & 15;
      int kk = k0 + kr;
      int h = kk / KH, k = kk % KH;
      float4 v = *reinterpret_cast<const float4*>(&W[(size_t)k * OUTC + h * HID + cb + nq * 4]);
      *reinterpret_cast<float4*>(&sB[kr][nq * 4]) = v;
    }
    __syncthreads();
#pragma unroll 4
    for (int kk = 0; kk < BK; ++kk) {
      float4 a = *reinterpret_cast<const float4*>(&sAT[kk][m0]);
      float4 b = *reinterpret_cast<const float4*>(&sB[kk][n0]);
      acc[0][0] += a.x * b.x; acc[0][1] += a.x * b.y; acc[0][2] += a.x * b.z; acc[0][3] += a.x * b.w;
      acc[1][0] += a.y * b.x; acc[1][1] += a.y * b.y; acc[1][2] += a.y * b.z; acc[1][3] += a.y * b.w;
      acc[2][0] += a.z * b.x; acc[2][1] += a.z * b.y; acc[2][2] += a.z * b.z; acc[2][3] += a.z * b.w;
      acc[3][0] += a.w * b.x; acc[3][1] += a.w * b.y; acc[3][2] += a.w * b.z; acc[3][3] += a.w * b.w;
    }
    __syncthreads();
  }
  float4 bv = *reinterpret_cast<const float4*>(&bias[cb + n0]);
#pragma unroll
  for (int i = 0; i < 4; ++i) {
    int row = r0 + m0 + i;
    if (row < NN) {
      float4 o;
      o.x = fmaxf(acc[i][0] + bv.x, 0.f);
      o.y = fmaxf(acc[i][1] + bv.y, 0.f);
      o.z = fmaxf(acc[i][2] + bv.z, 0.f);
      o.w = fmaxf(acc[i][3] + bv.w, 0.f);
      if (POOL) {
        float* gp = &gsums[(size_t)batch[row] * HID + cb + n0];
        atomicAdd(&gp[0], o.x); atomicAdd(&gp[1], o.y);
        atomicAdd(&gp[2], o.z); atomicAdd(&gp[3], o.w);
      } else {
        *reinterpret_cast<float4*>(&xout[(size_t)row * HID + cb + n0]) = o;
      }
    }
  }
}

// ---------------- MLP head (counts via binary search over sorted batch) ----------------
__global__ void k_mlp(const float* __restrict__ sums, const int* __restrict__ batch,
                      const float* __restrict__ bst, const float* __restrict__ M1,
                      const float* __restrict__ mb1, const float* __restrict__ M2,
                      const float* __restrict__ mb2, const float* __restrict__ M3,
                      const float* __restrict__ mb3, float* __restrict__ out) {
  int g = blockIdx.x, tid = threadIdx.x;  // 128 threads
  int lo = 0, hi = NN;
  while (lo < hi) { int mid = (lo + hi) >> 1; if (batch[mid] < g) lo = mid + 1; else hi = mid; }
  int s = lo;
  lo = s; hi = NN;
  while (lo < hi) { int mid = (lo + hi) >> 1; if (batch[mid] < g + 1) lo = mid + 1; else hi = mid; }
  int e = lo;
  float cnt = (float)(e - s);
  float pooled = sums[g * HID + tid] / fmaxf(cnt, 1.f);
  __shared__ float z[HID + 1];
  __shared__ float z1[HID];
  __shared__ float z2[64];
  z[tid] = pooled;
  if (tid == 0) z[HID] = log1pf(bst[g]);
  __syncthreads();
  float a1 = mb1[tid];
  for (int k = 0; k < HID + 1; ++k) a1 += z[k] * M1[k * HID + tid];
  z1[tid] = a1 > 0.f ? a1 : 0.f;
  __syncthreads();
  if (tid < 64) {
    float a2 = mb2[tid];
    for (int k = 0; k < HID; ++k) a2 += z1[k] * M2[k * 64 + tid];
    z2[tid] = a2 > 0.f ? a2 : 0.f;
  }
  __syncthreads();
  if (tid < 2) {
    float a3 = mb3[tid];
    for (int k = 0; k < 64; ++k) a3 += z2[k] * M3[k * 2 + tid];
    out[g * 2 + tid] = a3;
  }
}

extern "C" void kernel_launch(void* const* d_in, const int* in_sizes, int n_in,
                              void* d_out, int out_size, void* d_ws, size_t ws_size,
                              hipStream_t stream) {
  const float* x   = (const float*)d_in[0];
  const int*   ei  = (const int*)d_in[1];
  const int*   bat = (const int*)d_in[2];
  const float* bst = (const float*)d_in[3];
  const float* W1 = (const float*)d_in[4];
  const float* as1 = (const float*)d_in[5];
  const float* ad1 = (const float*)d_in[6];
  const float* b1 = (const float*)d_in[7];
  const float* W2 = (const float*)d_in[8];
  const float* as2 = (const float*)d_in[9];
  const float* ad2 = (const float*)d_in[10];
  const float* b2 = (const float*)d_in[11];
  const float* W3 = (const float*)d_in[12];
  const float* as3 = (const float*)d_in[13];
  const float* ad3 = (const float*)d_in[14];
  const float* b3 = (const float*)d_in[15];
  const float* M1 = (const float*)d_in[16];
  const float* mb1 = (const float*)d_in[17];
  const float* M2 = (const float*)d_in[18];
  const float* mb2 = (const float*)d_in[19];
  const float* M3 = (const float*)d_in[20];
  const float* mb3 = (const float*)d_in[21];
  float* out = (float*)d_out;

  char* ws = (char*)d_ws;
  auto alloc = [&](size_t bytes) -> void* {
    void* p = (void*)ws;
    ws += (bytes + 255) & ~(size_t)255;
    return p;
  };
  float* z_buf  = (float*)alloc((size_t)NN * OUTC * 4);   // aggregated x, 4 heads
  float* z1_buf = (float*)alloc((size_t)NN * 48 * 4);
  float* x_buf  = (float*)alloc((size_t)NN * HID * 4);
  float* e_src  = (float*)alloc((size_t)NN * 4 * 4);
  float* e_dst  = (float*)alloc((size_t)NN * 4 * 4);
  int*   deg    = (int*)alloc((size_t)NN * 4);
  int*   rowst  = (int*)alloc((size_t)(NN + 1) * 4);
  int*   cursor = (int*)alloc((size_t)NN * 4);
  int*   csr    = (int*)alloc((size_t)ET * 4);
  float* ealpha = (float*)alloc((size_t)ET * 4 * 4);
  float* invd   = (float*)alloc((size_t)NN * 4 * 4);
  float* watt   = (float*)alloc((size_t)HID * 8 * 4);
  float* gsums  = (float*)alloc((size_t)NG * HID * 4);

  // CSR by destination
  hipMemsetAsync(deg, 0, (size_t)NN * 4, stream);
  hipMemsetAsync(gsums, 0, (size_t)NG * HID * 4, stream);
  k_hist<<<(ET + 255) / 256, 256, 0, stream>>>(ei, deg);
  k_scan<<<1, 1024, 0, stream>>>(deg, rowst, cursor);
  k_scatter<<<(ET + 255) / 256, 256, 0, stream>>>(ei, cursor, csr);

  dim3 pgrid(NN / 4);
  dim3 ggrid(2, (NN + 63) / 64);
  // ---- layer 1 (K=12) ----
  k_watt<<<12, 256, 0, stream>>>(W1, as1, ad1, watt);
  k_esd1<<<(NN + 255) / 256, 256, 0, stream>>>(x, watt, e_src, e_dst);
  k_prep<<<pgrid, 256, 0, stream>>>(e_src, e_dst, rowst, csr, ealpha, invd);
  k_aggx1<<<pgrid, 256, 0, stream>>>(x, ealpha, invd, rowst, csr, z1_buf);
  k_gemm_z<48, 12, 48, 0><<<ggrid, 256, 0, stream>>>(z1_buf, W1, b1, bat, x_buf, gsums);
  // ---- layer 2 (K=128) ----
  k_watt<<<128, 256, 0, stream>>>(W2, as2, ad2, watt);
  k_esd128<<<512, 256, 0, stream>>>(x_buf, watt, e_src, e_dst);
  k_prep<<<pgrid, 256, 0, stream>>>(e_src, e_dst, rowst, csr, ealpha, invd);
  k_aggx128<<<pgrid, 256, 0, stream>>>(x_buf, ealpha, invd, rowst, csr, z_buf);
  k_gemm_z<512, 128, 64, 0><<<ggrid, 256, 0, stream>>>(z_buf, W2, b2, bat, x_buf, gsums);
  // ---- layer 3 (K=128, fused pool) ----
  k_watt<<<128, 256, 0, stream>>>(W3, as3, ad3, watt);
  k_esd128<<<512, 256, 0, stream>>>(x_buf, watt, e_src, e_dst);
  k_prep<<<pgrid, 256, 0, stream>>>(e_src, e_dst, rowst, csr, ealpha, invd);
  k_aggx128<<<pgrid, 256, 0, stream>>>(x_buf, ealpha, invd, rowst, csr, z_buf);
  k_gemm_z<512, 128, 64, 1><<<ggrid, 256, 0, stream>>>(z_buf, W3, b3, bat, x_buf, gsums);
  // ---- MLP head ----
  k_mlp<<<NG, 128, 0, stream>>>(gsums, bat, bst, M1, mb1, M2, mb2, M3, mb3, out);
}